// Round 1
// baseline (57.355 us; speedup 1.0000x reference)
//
#include <hip/hip_runtime.h>
#include <math.h>

#define B_TOTAL 4194304
#define NJ 6

// params layout per joint i: [ca, sa, a, d]
__global__ void fk_precompute_trig(const float* __restrict__ a,
                                   const float* __restrict__ d,
                                   const float* __restrict__ alpha,
                                   float* __restrict__ params) {
    int i = threadIdx.x;
    if (i < NJ) {
        params[i * 4 + 0] = cosf(alpha[i]);   // precise: feeds every row
        params[i * 4 + 1] = sinf(alpha[i]);
        params[i * 4 + 2] = a[i];
        params[i * 4 + 3] = d[i];
    }
}

__global__ void __launch_bounds__(256)
fk_kernel(const float* __restrict__ ja,
          const float* __restrict__ params,
          float* __restrict__ out) {
    int tid = blockIdx.x * blockDim.x + threadIdx.x;
    if (tid >= B_TOTAL) return;

    const float2* jap = reinterpret_cast<const float2*>(ja + (size_t)tid * 6);
    float2 j01 = jap[0];
    float2 j23 = jap[1];
    float2 j45 = jap[2];
    float th[6] = { j01.x, j01.y, j23.x, j23.y, j45.x, j45.y };

    // cur = identity (3x4 affine; bottom row is implicitly [0,0,0,1])
    float m00 = 1.f, m01 = 0.f, m02 = 0.f, m03 = 0.f;
    float m10 = 0.f, m11 = 1.f, m12 = 0.f, m13 = 0.f;
    float m20 = 0.f, m21 = 0.f, m22 = 1.f, m23 = 0.f;

#pragma unroll
    for (int i = 0; i < NJ; ++i) {
        float st, ct;
        __sincosf(th[i], &st, &ct);
        float ca = params[i * 4 + 0];
        float sa = params[i * 4 + 1];
        float ai = params[i * 4 + 2];
        float di = params[i * 4 + 3];

        // T columns:
        //   col0 = ( ct,      st,     0 )
        //   col1 = (-st*ca,  ct*ca,  sa )
        //   col2 = ( st*sa, -ct*sa,  ca )
        //   col3 = ( ai*ct,  ai*st,  di )
        float t01 = -st * ca, t11 = ct * ca;
        float t02 =  st * sa, t12 = -ct * sa;
        float t03 =  ai * ct, t13 =  ai * st;

        float n00 = m00 * ct  + m01 * st;
        float n01 = m00 * t01 + m01 * t11 + m02 * sa;
        float n02 = m00 * t02 + m01 * t12 + m02 * ca;
        float n03 = m00 * t03 + m01 * t13 + m02 * di + m03;

        float n10 = m10 * ct  + m11 * st;
        float n11 = m10 * t01 + m11 * t11 + m12 * sa;
        float n12 = m10 * t02 + m11 * t12 + m12 * ca;
        float n13 = m10 * t03 + m11 * t13 + m12 * di + m13;

        float n20 = m20 * ct  + m21 * st;
        float n21 = m20 * t01 + m21 * t11 + m22 * sa;
        float n22 = m20 * t02 + m21 * t12 + m22 * ca;
        float n23 = m20 * t03 + m21 * t13 + m22 * di + m23;

        m00 = n00; m01 = n01; m02 = n02; m03 = n03;
        m10 = n10; m11 = n11; m12 = n12; m13 = n13;
        m20 = n20; m21 = n21; m22 = n22; m23 = n23;
    }

    // quaternion (reference semantics: only trace>0 branch, else zeros)
    float trace = m00 + m11 + m22;
    float qw, qx, qy, qz;
    if (trace > 0.f) {
        float s = sqrtf(trace + 1.f) * 2.f;
        qw = 0.25f * s;
        qx = (m21 - m12) / s;
        qy = (m02 - m20) / s;
        qz = (m10 - m01) / s;
    } else {
        qw = 0.f; qx = 0.f; qy = 0.f; qz = 0.f;
    }

    float* o = out + (size_t)tid * 7;
    o[0] = m03;
    o[1] = m13;
    o[2] = m23;
    o[3] = qw;
    o[4] = qx;
    o[5] = qy;
    o[6] = qz;
}

extern "C" void kernel_launch(void* const* d_in, const int* in_sizes, int n_in,
                              void* d_out, int out_size, void* d_ws, size_t ws_size,
                              hipStream_t stream) {
    const float* ja    = (const float*)d_in[0];
    const float* a     = (const float*)d_in[1];
    const float* d     = (const float*)d_in[2];
    const float* alpha = (const float*)d_in[3];
    float* out = (float*)d_out;
    float* params = (float*)d_ws;   // 24 floats

    fk_precompute_trig<<<1, 64, 0, stream>>>(a, d, alpha, params);

    int threads = 256;
    int blocks = (B_TOTAL + threads - 1) / threads;
    fk_kernel<<<blocks, threads, 0, stream>>>(ja, params, out);
}